// Round 1
// baseline (4658.827 us; speedup 1.0000x reference)
//
#include <hip/hip_runtime.h>
#include <hip/hip_bf16.h>
#include <math.h>

// ---------------- problem constants ----------------
#define B_ROWS   32768
#define F_DIM    512
#define H_DIM    256        // HSIZE
#define U_DIM    512        // GLU fc units
#define OUT_DIM  128
#define NSTEPS   5
#define EPS_BN   1e-5f
#define RELAX_C  1.5f
#define SQRT_HALF 0.70710678118654752440f

// GLU column permutation: permuted col c -> source col
__device__ __forceinline__ int glu_perm(int c) {
    return (c & 1) ? ((c >> 1) + 256) : (c >> 1);
}

// ---------------- prep kernels ----------------
// Compute BN scale/shift (scale = g*rsqrt(v+eps), shift = b - m*scale)
// ft params permuted for GLU pairing; att + bn0 unpermuted.
__global__ void prep_bn_kernel(
    const float* __restrict__ bn0_g, const float* __restrict__ bn0_b,
    const float* __restrict__ bn0_m, const float* __restrict__ bn0_v,
    const float* __restrict__ ft_g, const float* __restrict__ ft_b,
    const float* __restrict__ ft_m, const float* __restrict__ ft_v,
    const float* __restrict__ att_g, const float* __restrict__ att_b,
    const float* __restrict__ att_m, const float* __restrict__ att_v,
    float* __restrict__ sc0, float* __restrict__ sh0,
    float* __restrict__ ftS, float* __restrict__ ftH,
    float* __restrict__ attS, float* __restrict__ attH)
{
    int idx = blockIdx.x * blockDim.x + threadIdx.x;
    if (idx < 512) {
        float s = bn0_g[idx] * rsqrtf(bn0_v[idx] + EPS_BN);
        sc0[idx] = s;
        sh0[idx] = bn0_b[idx] - bn0_m[idx] * s;
    } else if (idx < 512 + 24 * 512) {            // 6 transformers * 4 blocks * 512
        int q = idx - 512;
        int tb = q >> 9;                           // t*4 + blk
        int c = q & 511;
        int src = tb * 512 + glu_perm(c);
        float s = ft_g[src] * rsqrtf(ft_v[src] + EPS_BN);
        ftS[q] = s;
        ftH[q] = ft_b[src] - ft_m[src] * s;
    } else if (idx < 512 + 24 * 512 + 5 * 512) {
        int q = idx - 512 - 24 * 512;
        float s = att_g[q] * rsqrtf(att_v[q] + EPS_BN);
        attS[q] = s;
        attH[q] = att_b[q] - att_m[q] * s;
    }
}

// Permute GLU weight columns: dst[r][c] = src[r][perm(c)], N = 512
__global__ void permute_w_kernel(const float* __restrict__ src,
                                 float* __restrict__ dst, int total)
{
    int i = blockIdx.x * blockDim.x + threadIdx.x;
    if (i < total) {
        int r = i >> 9, c = i & 511;
        dst[i] = src[(r << 9) + glu_perm(c)];
    }
}

// feats = bn0(features); prior = 1
__global__ void bn0_prior_kernel(const float* __restrict__ x,
                                 const float* __restrict__ sc,
                                 const float* __restrict__ sh,
                                 float* __restrict__ feats,
                                 float* __restrict__ prior)
{
    int i = blockIdx.x * blockDim.x + threadIdx.x;   // over B*512/4
    int base = i * 4;
    int c = base & 511;
    float4 xv = *(const float4*)(x + base);
    float4 o;
    o.x = xv.x * sc[c]     + sh[c];
    o.y = xv.y * sc[c + 1] + sh[c + 1];
    o.z = xv.z * sc[c + 2] + sh[c + 2];
    o.w = xv.w * sc[c + 3] + sh[c + 3];
    *(float4*)(feats + base) = o;
    *(float4*)(prior + base) = make_float4(1.f, 1.f, 1.f, 1.f);
}

__global__ void zero_kernel(float4* __restrict__ p, int n4)
{
    int i = blockIdx.x * blockDim.x + threadIdx.x;
    if (i < n4) p[i] = make_float4(0.f, 0.f, 0.f, 0.f);
}

// ---------------- GEMM + fused epilogue ----------------
// MODE 0: GLU            out(B x 256) = glu(bn(A@W))          [permuted W]
// MODE 1: GLU + residual out = res*sqrt(.5) + glu(bn(A@W))
// MODE 2: MODE1 + optional out_acc += relu(out) for cols < 128
// MODE 3: BN only        out(B x 512) = bn(A@W)
// MODE 4: bias           out(B x 128) = A@W + shift
#define BM 128
#define BN 128
#define BK 16

template<int MODE>
__global__ __launch_bounds__(256) void gemm_epi(
    const float* __restrict__ A, int lda, int K,
    const float* __restrict__ W, int ldw,
    const float* __restrict__ scale, const float* __restrict__ shift,
    const float* __restrict__ res,
    float* __restrict__ out,
    float* __restrict__ out_acc)
{
    __shared__ float As[BK][BM];
    __shared__ float Bs[BK][BN];
    const int tid = threadIdx.x;
    const int tm = tid >> 4, tn = tid & 15;
    const int brow = blockIdx.y * BM;
    const int bcol = blockIdx.x * BN;

    float acc[8][8] = {};

    for (int k0 = 0; k0 < K; k0 += BK) {
        // A tile: 128 rows x 16 k, stored transposed As[k][m]
        #pragma unroll
        for (int i = 0; i < 2; ++i) {
            int f = tid + i * 256;            // 0..511
            int row = f >> 2;
            int kq = (f & 3) << 2;
            float4 av = *(const float4*)(A + (size_t)(brow + row) * lda + k0 + kq);
            As[kq + 0][row] = av.x;
            As[kq + 1][row] = av.y;
            As[kq + 2][row] = av.z;
            As[kq + 3][row] = av.w;
        }
        // W tile: 16 k x 128 n
        #pragma unroll
        for (int i = 0; i < 2; ++i) {
            int f = tid + i * 256;
            int kr = f >> 5;
            int nq = (f & 31) << 2;
            float4 wv = *(const float4*)(W + (size_t)(k0 + kr) * ldw + bcol + nq);
            *(float4*)(&Bs[kr][nq]) = wv;
        }
        __syncthreads();
        #pragma unroll
        for (int kk = 0; kk < BK; ++kk) {
            float a[8], b[8];
            *(float4*)(a)     = *(const float4*)(&As[kk][tm * 8]);
            *(float4*)(a + 4) = *(const float4*)(&As[kk][tm * 8 + 4]);
            *(float4*)(b)     = *(const float4*)(&Bs[kk][tn * 8]);
            *(float4*)(b + 4) = *(const float4*)(&Bs[kk][tn * 8 + 4]);
            #pragma unroll
            for (int i = 0; i < 8; ++i)
                #pragma unroll
                for (int j = 0; j < 8; ++j)
                    acc[i][j] += a[i] * b[j];
        }
        __syncthreads();
    }

    const int n0 = bcol + tn * 8;
    if constexpr (MODE <= 2) {
        const int ob = n0 >> 1;   // first of this thread's 4 output columns
        #pragma unroll
        for (int i = 0; i < 8; ++i) {
            int row = brow + tm * 8 + i;
            #pragma unroll
            for (int jj = 0; jj < 4; ++jj) {
                float y0 = acc[i][2 * jj]     * scale[n0 + 2 * jj]     + shift[n0 + 2 * jj];
                float y1 = acc[i][2 * jj + 1] * scale[n0 + 2 * jj + 1] + shift[n0 + 2 * jj + 1];
                float g = y0 / (1.0f + expf(-y1));      // y0 * sigmoid(y1)
                int oc = ob + jj;
                float val = g;
                if constexpr (MODE >= 1) val += res[(size_t)row * 256 + oc] * SQRT_HALF;
                out[(size_t)row * 256 + oc] = val;
                if constexpr (MODE == 2) {
                    if (out_acc && oc < 128)
                        out_acc[(size_t)row * 128 + oc] += fmaxf(val, 0.0f);
                }
            }
        }
    } else if constexpr (MODE == 3) {
        #pragma unroll
        for (int i = 0; i < 8; ++i) {
            int row = brow + tm * 8 + i;
            #pragma unroll
            for (int j = 0; j < 8; ++j) {
                int c = n0 + j;
                out[(size_t)row * 512 + c] = acc[i][j] * scale[c] + shift[c];
            }
        }
    } else {
        #pragma unroll
        for (int i = 0; i < 8; ++i) {
            int row = brow + tm * 8 + i;
            #pragma unroll
            for (int j = 0; j < 8; ++j)
                out[(size_t)row * 128 + n0 + j] = acc[i][j] + shift[n0 + j];
        }
    }
}

// ---------------- fused sparsemax ----------------
// attmf holds att (B x 512) on entry; on exit holds mask*feats.
// One wave per row. z = att*prior; binary search tau; mask = max(z-tau,0);
// prior *= (RELAX - mask); mask -> d_out.
__global__ __launch_bounds__(256) void sparsemax_kernel(
    const float* __restrict__ feats,
    float* __restrict__ attmf,
    float* __restrict__ prior,
    float* __restrict__ mask_out)
{
    const int lane = threadIdx.x & 63;
    const int wid = threadIdx.x >> 6;
    const int row = blockIdx.x * 4 + wid;
    const size_t base = (size_t)row * 512 + lane;

    float z[8], pr[8];
    #pragma unroll
    for (int j = 0; j < 8; ++j) {
        pr[j] = prior[base + j * 64];
        z[j] = attmf[base + j * 64] * pr[j];
    }
    float mx = z[0];
    #pragma unroll
    for (int j = 1; j < 8; ++j) mx = fmaxf(mx, z[j]);
    #pragma unroll
    for (int off = 32; off; off >>= 1) mx = fmaxf(mx, __shfl_xor(mx, off));

    float lo = mx - 1.0f, hi = mx;
    #pragma unroll 4
    for (int it = 0; it < 32; ++it) {
        float mid = 0.5f * (lo + hi);
        float s = 0.f;
        #pragma unroll
        for (int j = 0; j < 8; ++j) s += fmaxf(z[j] - mid, 0.f);
        #pragma unroll
        for (int off = 32; off; off >>= 1) s += __shfl_xor(s, off);
        if (s >= 1.0f) lo = mid; else hi = mid;
    }
    const float tau = lo;

    #pragma unroll
    for (int j = 0; j < 8; ++j) {
        float m = fmaxf(z[j] - tau, 0.f);
        mask_out[base + j * 64] = m;
        prior[base + j * 64] = pr[j] * (RELAX_C - m);
        attmf[base + j * 64] = m * feats[base + j * 64];
    }
}

// ---------------- launch ----------------
extern "C" void kernel_launch(void* const* d_in, const int* in_sizes, int n_in,
                              void* d_out, int out_size, void* d_ws, size_t ws_size,
                              hipStream_t stream)
{
    const float* features = (const float*)d_in[0];
    const float* bn0_g = (const float*)d_in[1];
    const float* bn0_b = (const float*)d_in[2];
    const float* bn0_m = (const float*)d_in[3];
    const float* bn0_v = (const float*)d_in[4];
    const float* Ws0   = (const float*)d_in[5];
    const float* Ws1   = (const float*)d_in[6];
    const float* Wu    = (const float*)d_in[7];
    const float* ft_g  = (const float*)d_in[8];
    const float* ft_b  = (const float*)d_in[9];
    const float* ft_m  = (const float*)d_in[10];
    const float* ft_v  = (const float*)d_in[11];
    const float* W_att = (const float*)d_in[12];
    const float* att_g = (const float*)d_in[13];
    const float* att_b = (const float*)d_in[14];
    const float* att_m = (const float*)d_in[15];
    const float* att_v = (const float*)d_in[16];
    const float* Wf    = (const float*)d_in[17];
    const float* bf    = (const float*)d_in[18];

    float* out = (float*)d_out;

    // ws layout (floats)
    float* ws_f  = (float*)d_ws;
    float* feats = ws_f;                       // B*512
    float* ubuf  = feats + 16777216;           // B*256
    float* vbuf  = ubuf  + 8388608;            // B*256
    float* attmf = vbuf  + 8388608;            // B*512 (att then mask*feats)
    float* prior = attmf + 16777216;           // B*512
    float* oacc  = prior + 16777216;           // B*128
    float* ws0p  = oacc  + 4194304;            // 512*512
    float* ws1p  = ws0p  + 262144;             // 256*512
    float* wup   = ws1p  + 131072;             // 6*2*256*512
    float* ftS   = wup   + 1572864;            // 24*512
    float* ftH   = ftS   + 12288;
    float* attS  = ftH   + 12288;              // 5*512
    float* attH  = attS  + 2560;
    float* sc0   = attH  + 2560;               // 512
    float* sh0   = sc0   + 512;

    // ---- prep ----
    prep_bn_kernel<<<(512 + 24 * 512 + 5 * 512 + 255) / 256, 256, 0, stream>>>(
        bn0_g, bn0_b, bn0_m, bn0_v, ft_g, ft_b, ft_m, ft_v,
        att_g, att_b, att_m, att_v, sc0, sh0, ftS, ftH, attS, attH);
    permute_w_kernel<<<262144 / 256, 256, 0, stream>>>(Ws0, ws0p, 262144);
    permute_w_kernel<<<131072 / 256, 256, 0, stream>>>(Ws1, ws1p, 131072);
    permute_w_kernel<<<1572864 / 256, 256, 0, stream>>>(Wu, wup, 1572864);
    bn0_prior_kernel<<<(B_ROWS * 512 / 4) / 256, 256, 0, stream>>>(
        features, sc0, sh0, feats, prior);
    zero_kernel<<<(B_ROWS * 128 / 4) / 256, 256, 0, stream>>>((float4*)oacc, B_ROWS * 128 / 4);

    const dim3 g512(4, B_ROWS / BM);   // N=512 gemms
    const dim3 g128(1, B_ROWS / BM);   // N=128 final

    auto ft_launch = [&](const float* in, int t, bool accum) {
        const float* wu_t0 = wup + (size_t)(t * 2 + 0) * 256 * 512;
        const float* wu_t1 = wup + (size_t)(t * 2 + 1) * 256 * 512;
        gemm_epi<0><<<g512, 256, 0, stream>>>(in, 512, 512, ws0p, 512,
            ftS + (t * 4 + 0) * 512, ftH + (t * 4 + 0) * 512, nullptr, ubuf, nullptr);
        gemm_epi<1><<<g512, 256, 0, stream>>>(ubuf, 256, 256, ws1p, 512,
            ftS + (t * 4 + 1) * 512, ftH + (t * 4 + 1) * 512, ubuf, vbuf, nullptr);
        gemm_epi<1><<<g512, 256, 0, stream>>>(vbuf, 256, 256, wu_t0, 512,
            ftS + (t * 4 + 2) * 512, ftH + (t * 4 + 2) * 512, vbuf, ubuf, nullptr);
        gemm_epi<2><<<g512, 256, 0, stream>>>(ubuf, 256, 256, wu_t1, 512,
            ftS + (t * 4 + 3) * 512, ftH + (t * 4 + 3) * 512, ubuf, vbuf,
            accum ? oacc : nullptr);
    };

    // T0 on bn'd features
    ft_launch(feats, 0, false);

    for (int s = 0; s < NSTEPS; ++s) {
        // att = bn(x[:,128:256] @ W_att[s])  -> attmf
        gemm_epi<3><<<g512, 256, 0, stream>>>(vbuf + 128, 256, 128,
            W_att + (size_t)s * 128 * 512, 512,
            attS + s * 512, attH + s * 512, nullptr, attmf, nullptr);
        // sparsemax + prior update + mask out + masked feats (in-place attmf)
        sparsemax_kernel<<<B_ROWS / 4, 256, 0, stream>>>(
            feats, attmf, prior,
            out + 4194304 + (size_t)s * 16777216);
        // next transformer on mask*feats
        ft_launch(attmf, s + 1, true);
    }

    // final = out_acc @ Wf + bf
    gemm_epi<4><<<g128, 256, 0, stream>>>(oacc, 128, 128, Wf, 128,
        nullptr, bf, nullptr, out, nullptr);
}

// Round 2
// 2230.380 us; speedup vs baseline: 2.0888x; 2.0888x over previous
//
#include <hip/hip_runtime.h>
#include <hip/hip_bf16.h>
#include <math.h>

#define B_ROWS   32768
#define NSTEPS   5
#define EPS_BN   1e-5f
#define RELAX_C  1.5f
#define SQRT_HALF 0.70710678118654752440f

typedef _Float16 f16;
typedef _Float16 f16x4 __attribute__((ext_vector_type(4)));
typedef _Float16 f16x8 __attribute__((ext_vector_type(8)));
typedef float    f32x4 __attribute__((ext_vector_type(4)));

// GLU pairing permutation: permuted col c -> source col.
// Within each 32-col group g: positions 0..15 = y0 (src g*16+o), 16..31 = y1 (src g*16+o+256).
__device__ __forceinline__ int glu_perm2(int c) {
    int g = c >> 5, o = c & 31;
    return (o < 16) ? (g * 16 + o) : (g * 16 + (o - 16) + 256);
}

__device__ __forceinline__ void gload16(const void* g, void* l) {
    __builtin_amdgcn_global_load_lds(
        (const __attribute__((address_space(1))) unsigned int*)g,
        (__attribute__((address_space(3))) unsigned int*)l, 16, 0, 0);
}

__device__ __forceinline__ void split_write(f16* __restrict__ hi, f16* __restrict__ lo,
                                            size_t idx, float v) {
    f16 h = (f16)v;
    hi[idx] = h;
    lo[idx] = (f16)(v - (float)h);
}

// ---------------- prep kernels ----------------
__global__ void prep_bn_kernel(
    const float* __restrict__ bn0_g, const float* __restrict__ bn0_b,
    const float* __restrict__ bn0_m, const float* __restrict__ bn0_v,
    const float* __restrict__ ft_g, const float* __restrict__ ft_b,
    const float* __restrict__ ft_m, const float* __restrict__ ft_v,
    const float* __restrict__ att_g, const float* __restrict__ att_b,
    const float* __restrict__ att_m, const float* __restrict__ att_v,
    float* __restrict__ sc0, float* __restrict__ sh0,
    float* __restrict__ ftS, float* __restrict__ ftH,
    float* __restrict__ attS, float* __restrict__ attH)
{
    int idx = blockIdx.x * blockDim.x + threadIdx.x;
    if (idx < 512) {
        float s = bn0_g[idx] * rsqrtf(bn0_v[idx] + EPS_BN);
        sc0[idx] = s;
        sh0[idx] = bn0_b[idx] - bn0_m[idx] * s;
    } else if (idx < 512 + 24 * 512) {
        int q = idx - 512;
        int tb = q >> 9;
        int c = q & 511;
        int src = tb * 512 + glu_perm2(c);
        float s = ft_g[src] * rsqrtf(ft_v[src] + EPS_BN);
        ftS[q] = s;
        ftH[q] = ft_b[src] - ft_m[src] * s;
    } else if (idx < 512 + 24 * 512 + 5 * 512) {
        int q = idx - 512 - 24 * 512;
        float s = att_g[q] * rsqrtf(att_v[q] + EPS_BN);
        attS[q] = s;
        attH[q] = att_b[q] - att_m[q] * s;
    }
}

// Weight prep: src [K][512] fp32 row-major -> dst [512][K] fp16 hi/lo planes (optionally GLU-permuted cols)
__global__ void wprep_kernel(const float* __restrict__ src,
                             f16* __restrict__ dh, f16* __restrict__ dl,
                             int K, int doperm)
{
    int i = blockIdx.x * blockDim.x + threadIdx.x;
    if (i >= 512 * K) return;
    int n = i / K, k = i - n * K;
    int sn = doperm ? glu_perm2(n) : n;
    float v = src[(size_t)k * 512 + sn];
    f16 h = (f16)v;
    dh[i] = h;
    dl[i] = (f16)(v - (float)h);
}

// feats = bn0(features) -> split planes; prior = 1
__global__ void bn0_split_kernel(const float* __restrict__ x,
                                 const float* __restrict__ sc,
                                 const float* __restrict__ sh,
                                 f16* __restrict__ fh, f16* __restrict__ fl,
                                 float* __restrict__ prior)
{
    int i = blockIdx.x * blockDim.x + threadIdx.x;   // over B*512/4
    int base = i * 4;
    int c = base & 511;
    float4 xv = *(const float4*)(x + base);
    float o0 = xv.x * sc[c]     + sh[c];
    float o1 = xv.y * sc[c + 1] + sh[c + 1];
    float o2 = xv.z * sc[c + 2] + sh[c + 2];
    float o3 = xv.w * sc[c + 3] + sh[c + 3];
    f16x4 hv, lv;
    hv.x = (f16)o0; lv.x = (f16)(o0 - (float)hv.x);
    hv.y = (f16)o1; lv.y = (f16)(o1 - (float)hv.y);
    hv.z = (f16)o2; lv.z = (f16)(o2 - (float)hv.z);
    hv.w = (f16)o3; lv.w = (f16)(o3 - (float)hv.w);
    *(f16x4*)(fh + base) = hv;
    *(f16x4*)(fl + base) = lv;
    *(float4*)(prior + base) = make_float4(1.f, 1.f, 1.f, 1.f);
}

__global__ void zero_kernel(float4* __restrict__ p, int n4)
{
    int i = blockIdx.x * blockDim.x + threadIdx.x;
    if (i < n4) p[i] = make_float4(0.f, 0.f, 0.f, 0.f);
}

// ---------------- split-fp16 MFMA GEMM + fused epilogue ----------------
// Tile 128x128, BK=32, 4 waves (2x2), double-buffered LDS via global_load_lds.
// A: split planes [B][ldA] fp16 hi/lo. B: split planes [512][K] (pre-transposed).
// MODE 0: out = glu(bn(A@W))            -> out planes [B][256]
// MODE 1: out = res*sqrt(.5)+glu(bn(.)) -> out planes
// MODE 2: MODE1 + oacc += relu(out) for oc<128
// MODE 3: outf = bn(A@W)                -> fp32 [B][512]
template<int MODE>
__global__ __launch_bounds__(256, 2) void gemm_mfma(
    const f16* __restrict__ Ah, const f16* __restrict__ Al, int ldA, int K,
    const f16* __restrict__ Bh, const f16* __restrict__ Bl,
    const float* __restrict__ scale, const float* __restrict__ shift,
    const f16* __restrict__ resh, const f16* __restrict__ resl,
    f16* __restrict__ outh, f16* __restrict__ outl,
    float* __restrict__ outf,
    float* __restrict__ oacc)
{
    __shared__ __align__(16) char smem[65536];   // 2 x 32KB buffers
    const int tid  = threadIdx.x;
    const int lane = tid & 63;
    const int w    = tid >> 6;        // wave 0..3
    const int wm   = w >> 1, wn = w & 1;
    const int brow = blockIdx.y * 128;
    const int bcol = blockIdx.x * 128;
    const int lrow = lane & 15;
    const int lk8  = (lane >> 4) * 8;
    const int s0   = w * 2, s1 = w * 2 + 1;

    // staging sources: slot s holds rows/cols base+s*16+lrow, halves k0+lk8..+8
    const char* gsrc[8];
    gsrc[0] = (const char*)(Ah + (size_t)(brow + s0 * 16 + lrow) * ldA + lk8);
    gsrc[1] = (const char*)(Ah + (size_t)(brow + s1 * 16 + lrow) * ldA + lk8);
    gsrc[2] = (const char*)(Al + (size_t)(brow + s0 * 16 + lrow) * ldA + lk8);
    gsrc[3] = (const char*)(Al + (size_t)(brow + s1 * 16 + lrow) * ldA + lk8);
    gsrc[4] = (const char*)(Bh + (size_t)(bcol + s0 * 16 + lrow) * K + lk8);
    gsrc[5] = (const char*)(Bh + (size_t)(bcol + s1 * 16 + lrow) * K + lk8);
    gsrc[6] = (const char*)(Bl + (size_t)(bcol + s0 * 16 + lrow) * K + lk8);
    gsrc[7] = (const char*)(Bl + (size_t)(bcol + s1 * 16 + lrow) * K + lk8);
    int ldst[8];
    ldst[0] = s0 * 1024;          ldst[1] = s1 * 1024;
    ldst[2] = 8192 + s0 * 1024;   ldst[3] = 8192 + s1 * 1024;
    ldst[4] = 16384 + s0 * 1024;  ldst[5] = 16384 + s1 * 1024;
    ldst[6] = 24576 + s0 * 1024;  ldst[7] = 24576 + s1 * 1024;

    f32x4 acc[4][4];
    #pragma unroll
    for (int m = 0; m < 4; ++m)
        #pragma unroll
        for (int n = 0; n < 4; ++n)
            acc[m][n] = f32x4{0.f, 0.f, 0.f, 0.f};

    const int NT = K >> 5;
    #pragma unroll
    for (int i = 0; i < 8; ++i) gload16(gsrc[i], smem + ldst[i]);

    for (int t = 0; t < NT; ++t) {
        __syncthreads();     // drains vmcnt: buf[t&1] staged; prior reads done
        if (t + 1 < NT) {
            const int bo = ((t + 1) & 1) * 32768;
            const int ko = (t + 1) * 64;
            #pragma unroll
            for (int i = 0; i < 8; ++i) gload16(gsrc[i] + ko, smem + bo + ldst[i]);
        }
        const char* L = smem + (t & 1) * 32768;
        f16x8 ah[4], al[4];
        #pragma unroll
        for (int m = 0; m < 4; ++m) {
            const int so = (wm * 4 + m) * 1024 + lane * 16;
            ah[m] = *(const f16x8*)(L + so);
            al[m] = *(const f16x8*)(L + 8192 + so);
        }
        #pragma unroll
        for (int n = 0; n < 4; ++n) {
            const int so = (wn * 4 + n) * 1024 + lane * 16;
            f16x8 bh = *(const f16x8*)(L + 16384 + so);
            f16x8 bl = *(const f16x8*)(L + 24576 + so);
            #pragma unroll
            for (int m = 0; m < 4; ++m) {
                acc[m][n] = __builtin_amdgcn_mfma_f32_16x16x32_f16(ah[m], bh, acc[m][n], 0, 0, 0);
                acc[m][n] = __builtin_amdgcn_mfma_f32_16x16x32_f16(ah[m], bl, acc[m][n], 0, 0, 0);
                acc[m][n] = __builtin_amdgcn_mfma_f32_16x16x32_f16(al[m], bh, acc[m][n], 0, 0, 0);
            }
        }
    }

    // epilogue: D[m'][n'] m' = (lane>>4)*4+r, n' = lane&15 within fragment
    if constexpr (MODE <= 2) {
        #pragma unroll
        for (int p = 0; p < 2; ++p) {
            const int cb = bcol + wn * 64 + p * 32;     // even fragment base (mult of 32)
            const float sA = scale[cb + lrow],      hA = shift[cb + lrow];
            const float sB = scale[cb + 16 + lrow], hB = shift[cb + 16 + lrow];
            const int oc = (cb >> 1) + lrow;
            #pragma unroll
            for (int m = 0; m < 4; ++m) {
                const int row0 = brow + wm * 64 + m * 16 + (lane >> 4) * 4;
                #pragma unroll
                for (int r = 0; r < 4; ++r) {
                    const int row = row0 + r;
                    float y0 = acc[m][2 * p][r]     * sA + hA;
                    float y1 = acc[m][2 * p + 1][r] * sB + hB;
                    float val = y0 / (1.f + expf(-y1));
                    const size_t oi = (size_t)row * 256 + oc;
                    if constexpr (MODE >= 1)
                        val += SQRT_HALF * ((float)resh[oi] + (float)resl[oi]);
                    split_write(outh, outl, oi, val);
                    if constexpr (MODE == 2) {
                        if (oc < 128) oacc[(size_t)row * 128 + oc] += fmaxf(val, 0.f);
                    }
                }
            }
        }
    } else {
        #pragma unroll
        for (int n = 0; n < 4; ++n) {
            const int c = bcol + wn * 64 + n * 16 + lrow;
            const float sA = scale[c], hA = shift[c];
            #pragma unroll
            for (int m = 0; m < 4; ++m) {
                const int row0 = brow + wm * 64 + m * 16 + (lane >> 4) * 4;
                #pragma unroll
                for (int r = 0; r < 4; ++r)
                    outf[(size_t)(row0 + r) * 512 + c] = acc[m][n][r] * sA + hA;
            }
        }
    }
}

// ---------------- fused sparsemax ----------------
// attm (in d_out mask slot): holds att on entry, mask on exit.
__global__ __launch_bounds__(256) void sparsemax_kernel(
    const f16* __restrict__ fh, const f16* __restrict__ fl,
    float* __restrict__ attm,
    float* __restrict__ prior,
    f16* __restrict__ mh, f16* __restrict__ ml)
{
    const int lane = threadIdx.x & 63;
    const int wid = threadIdx.x >> 6;
    const int row = blockIdx.x * 4 + wid;
    const size_t base = (size_t)row * 512 + lane;

    float z[8], pr[8];
    #pragma unroll
    for (int j = 0; j < 8; ++j) {
        pr[j] = prior[base + j * 64];
        z[j] = attm[base + j * 64] * pr[j];
    }
    float mx = z[0];
    #pragma unroll
    for (int j = 1; j < 8; ++j) mx = fmaxf(mx, z[j]);
    #pragma unroll
    for (int off = 32; off; off >>= 1) mx = fmaxf(mx, __shfl_xor(mx, off));

    float lo = mx - 1.0f, hi = mx;
    #pragma unroll 4
    for (int it = 0; it < 32; ++it) {
        float mid = 0.5f * (lo + hi);
        float s = 0.f;
        #pragma unroll
        for (int j = 0; j < 8; ++j) s += fmaxf(z[j] - mid, 0.f);
        #pragma unroll
        for (int off = 32; off; off >>= 1) s += __shfl_xor(s, off);
        if (s >= 1.0f) lo = mid; else hi = mid;
    }
    const float tau = lo;

    #pragma unroll
    for (int j = 0; j < 8; ++j) {
        const size_t ix = base + j * 64;
        float m = fmaxf(z[j] - tau, 0.f);
        attm[ix] = m;
        prior[ix] = pr[j] * (RELAX_C - m);
        float f = (float)fh[ix] + (float)fl[ix];
        split_write(mh, ml, ix, m * f);
    }
}

// ---------------- final fp32 SIMT GEMM (K=128, N=128) ----------------
__global__ __launch_bounds__(256) void gemm_f32_final(
    const float* __restrict__ A,     // [B][128]
    const float* __restrict__ W,     // [128][128]
    const float* __restrict__ bias,
    float* __restrict__ out)         // [B][128]
{
    __shared__ float As[16][128];
    __shared__ float Bs[16][128];
    const int tid = threadIdx.x;
    const int tm = tid >> 4, tn = tid & 15;
    const int brow = blockIdx.x * 128;
    float acc[8][8] = {};
    for (int k0 = 0; k0 < 128; k0 += 16) {
        #pragma unroll
        for (int i = 0; i < 2; ++i) {
            int f = tid + i * 256;
            int row = f >> 2, kq = (f & 3) << 2;
            float4 av = *(const float4*)(A + (size_t)(brow + row) * 128 + k0 + kq);
            As[kq + 0][row] = av.x;
            As[kq + 1][row] = av.y;
            As[kq + 2][row] = av.z;
            As[kq + 3][row] = av.w;
            int kr = f >> 5, nq = (f & 31) << 2;
            *(float4*)(&Bs[kr][nq]) = *(const float4*)(W + (size_t)(k0 + kr) * 128 + nq);
        }
        __syncthreads();
        #pragma unroll
        for (int kk = 0; kk < 16; ++kk) {
            float a[8], b[8];
            *(float4*)(a)     = *(const float4*)(&As[kk][tm * 8]);
            *(float4*)(a + 4) = *(const float4*)(&As[kk][tm * 8 + 4]);
            *(float4*)(b)     = *(const float4*)(&Bs[kk][tn * 8]);
            *(float4*)(b + 4) = *(const float4*)(&Bs[kk][tn * 8 + 4]);
            #pragma unroll
            for (int i = 0; i < 8; ++i)
                #pragma unroll
                for (int j = 0; j < 8; ++j)
                    acc[i][j] += a[i] * b[j];
        }
        __syncthreads();
    }
    #pragma unroll
    for (int i = 0; i < 8; ++i) {
        int row = brow + tm * 8 + i;
        #pragma unroll
        for (int j = 0; j < 8; ++j)
            out[(size_t)row * 128 + tn * 8 + j] = acc[i][j] + bias[tn * 8 + j];
    }
}

// ---------------- launch ----------------
extern "C" void kernel_launch(void* const* d_in, const int* in_sizes, int n_in,
                              void* d_out, int out_size, void* d_ws, size_t ws_size,
                              hipStream_t stream)
{
    const float* features = (const float*)d_in[0];
    const float* bn0_g = (const float*)d_in[1];
    const float* bn0_b = (const float*)d_in[2];
    const float* bn0_m = (const float*)d_in[3];
    const float* bn0_v = (const float*)d_in[4];
    const float* Ws0   = (const float*)d_in[5];
    const float* Ws1   = (const float*)d_in[6];
    const float* Wu    = (const float*)d_in[7];
    const float* ft_g  = (const float*)d_in[8];
    const float* ft_b  = (const float*)d_in[9];
    const float* ft_m  = (const float*)d_in[10];
    const float* ft_v  = (const float*)d_in[11];
    const float* W_att = (const float*)d_in[12];
    const float* att_g = (const float*)d_in[13];
    const float* att_b = (const float*)d_in[14];
    const float* att_m = (const float*)d_in[15];
    const float* att_v = (const float*)d_in[16];
    const float* Wf    = (const float*)d_in[17];
    const float* bf    = (const float*)d_in[18];
    float* out = (float*)d_out;

    // ---- ws layout (bytes) ----
    char* wp = (char*)d_ws;
    auto alloc = [&](size_t bytes) { char* r = wp; wp += bytes; return r; };
    const size_t BR = B_ROWS;
    f16* feats_h = (f16*)alloc(BR * 512 * 2);
    f16* feats_l = (f16*)alloc(BR * 512 * 2);
    f16* ubuf_h  = (f16*)alloc(BR * 256 * 2);
    f16* ubuf_l  = (f16*)alloc(BR * 256 * 2);
    f16* vbuf_h  = (f16*)alloc(BR * 256 * 2);
    f16* vbuf_l  = (f16*)alloc(BR * 256 * 2);
    f16* attmf_h = (f16*)alloc(BR * 512 * 2);
    f16* attmf_l = (f16*)alloc(BR * 512 * 2);
    float* prior = (float*)alloc(BR * 512 * 4);
    float* oacc  = (float*)alloc(BR * 128 * 4);
    f16* ws0_h = (f16*)alloc(512 * 512 * 2);
    f16* ws0_l = (f16*)alloc(512 * 512 * 2);
    f16* ws1_h = (f16*)alloc(512 * 256 * 2);
    f16* ws1_l = (f16*)alloc(512 * 256 * 2);
    f16* wu_h  = (f16*)alloc((size_t)12 * 512 * 256 * 2);
    f16* wu_l  = (f16*)alloc((size_t)12 * 512 * 256 * 2);
    f16* wat_h = (f16*)alloc((size_t)5 * 512 * 128 * 2);
    f16* wat_l = (f16*)alloc((size_t)5 * 512 * 128 * 2);
    float* ftS  = (float*)alloc(24 * 512 * 4);
    float* ftH  = (float*)alloc(24 * 512 * 4);
    float* attS = (float*)alloc(5 * 512 * 4);
    float* attH = (float*)alloc(5 * 512 * 4);
    float* sc0  = (float*)alloc(512 * 4);
    float* sh0  = (float*)alloc(512 * 4);

    // ---- prep ----
    prep_bn_kernel<<<60, 256, 0, stream>>>(
        bn0_g, bn0_b, bn0_m, bn0_v, ft_g, ft_b, ft_m, ft_v,
        att_g, att_b, att_m, att_v, sc0, sh0, ftS, ftH, attS, attH);
    wprep_kernel<<<(512 * 512 + 255) / 256, 256, 0, stream>>>(Ws0, ws0_h, ws0_l, 512, 1);
    wprep_kernel<<<(512 * 256 + 255) / 256, 256, 0, stream>>>(Ws1, ws1_h, ws1_l, 256, 1);
    for (int th = 0; th < 12; ++th)
        wprep_kernel<<<(512 * 256 + 255) / 256, 256, 0, stream>>>(
            Wu + (size_t)th * 131072, wu_h + (size_t)th * 131072, wu_l + (size_t)th * 131072, 256, 1);
    for (int s = 0; s < 5; ++s)
        wprep_kernel<<<(512 * 128 + 255) / 256, 256, 0, stream>>>(
            W_att + (size_t)s * 65536, wat_h + (size_t)s * 65536, wat_l + (size_t)s * 65536, 128, 0);
    bn0_split_kernel<<<(B_ROWS * 512 / 4) / 256, 256, 0, stream>>>(
        features, sc0, sh0, feats_h, feats_l, prior);
    zero_kernel<<<(B_ROWS * 128 / 4) / 256, 256, 0, stream>>>((float4*)oacc, B_ROWS * 128 / 4);

    const dim3 grid(4, B_ROWS / 128);

    auto ft = [&](const f16* inh, const f16* inl, int ldin, int Kin, int t, bool accum) {
        const f16* wuh0 = wu_h + (size_t)(t * 2 + 0) * 131072;
        const f16* wul0 = wu_l + (size_t)(t * 2 + 0) * 131072;
        const f16* wuh1 = wu_h + (size_t)(t * 2 + 1) * 131072;
        const f16* wul1 = wu_l + (size_t)(t * 2 + 1) * 131072;
        gemm_mfma<0><<<grid, 256, 0, stream>>>(inh, inl, ldin, Kin, ws0_h, ws0_l,
            ftS + (t * 4 + 0) * 512, ftH + (t * 4 + 0) * 512,
            nullptr, nullptr, ubuf_h, ubuf_l, nullptr, nullptr);
        gemm_mfma<1><<<grid, 256, 0, stream>>>(ubuf_h, ubuf_l, 256, 256, ws1_h, ws1_l,
            ftS + (t * 4 + 1) * 512, ftH + (t * 4 + 1) * 512,
            ubuf_h, ubuf_l, vbuf_h, vbuf_l, nullptr, nullptr);
        gemm_mfma<1><<<grid, 256, 0, stream>>>(vbuf_h, vbuf_l, 256, 256, wuh0, wul0,
            ftS + (t * 4 + 2) * 512, ftH + (t * 4 + 2) * 512,
            vbuf_h, vbuf_l, ubuf_h, ubuf_l, nullptr, nullptr);
        if (accum)
            gemm_mfma<2><<<grid, 256, 0, stream>>>(ubuf_h, ubuf_l, 256, 256, wuh1, wul1,
                ftS + (t * 4 + 3) * 512, ftH + (t * 4 + 3) * 512,
                ubuf_h, ubuf_l, vbuf_h, vbuf_l, nullptr, oacc);
        else
            gemm_mfma<1><<<grid, 256, 0, stream>>>(ubuf_h, ubuf_l, 256, 256, wuh1, wul1,
                ftS + (t * 4 + 3) * 512, ftH + (t * 4 + 3) * 512,
                ubuf_h, ubuf_l, vbuf_h, vbuf_l, nullptr, nullptr);
    };

    ft(feats_h, feats_l, 512, 512, 0, false);

    for (int s = 0; s < NSTEPS; ++s) {
        float* attm = out + 4194304 + (size_t)s * 16777216;   // att, then mask (in-place)
        gemm_mfma<3><<<grid, 256, 0, stream>>>(vbuf_h + 128, vbuf_l + 128, 256, 128,
            wat_h + (size_t)s * 65536, wat_l + (size_t)s * 65536,
            attS + s * 512, attH + s * 512,
            nullptr, nullptr, nullptr, nullptr, attm, nullptr);
        sparsemax_kernel<<<B_ROWS / 4, 256, 0, stream>>>(
            feats_h, feats_l, attm, prior, attmf_h, attmf_l);
        ft(attmf_h, attmf_l, 512, 512, s + 1, true);
    }

    gemm_f32_final<<<B_ROWS / 128, 256, 0, stream>>>(oacc, Wf, bf, out);
}

// Round 3
// 1312.243 us; speedup vs baseline: 3.5503x; 1.6997x over previous
//
#include <hip/hip_runtime.h>
#include <hip/hip_bf16.h>
#include <math.h>

#define B_ROWS   32768
#define NSTEPS   5
#define EPS_BN   1e-5f
#define RELAX_C  1.5f
#define SQRT_HALF 0.70710678118654752440f

typedef _Float16 f16;
typedef _Float16 f16x4 __attribute__((ext_vector_type(4)));
typedef _Float16 f16x8 __attribute__((ext_vector_type(8)));
typedef float    f32x4 __attribute__((ext_vector_type(4)));

// GLU pairing permutation: permuted col c -> source col.
// Within each 32-col group g: positions 0..15 = y0 (src g*16+o), 16..31 = gate (src g*16+(o-16)+256).
__device__ __forceinline__ int glu_perm2(int c) {
    int g = c >> 5, o = c & 31;
    return (o < 16) ? (g * 16 + o) : (g * 16 + (o - 16) + 256);
}

__device__ __forceinline__ void gload16(const void* g, void* l) {
    __builtin_amdgcn_global_load_lds(
        (const __attribute__((address_space(1))) unsigned int*)g,
        (__attribute__((address_space(3))) unsigned int*)l, 16, 0, 0);
}

// ---------------- prep kernels ----------------
__global__ void prep_bn_kernel(
    const float* __restrict__ bn0_g, const float* __restrict__ bn0_b,
    const float* __restrict__ bn0_m, const float* __restrict__ bn0_v,
    const float* __restrict__ ft_g, const float* __restrict__ ft_b,
    const float* __restrict__ ft_m, const float* __restrict__ ft_v,
    const float* __restrict__ att_g, const float* __restrict__ att_b,
    const float* __restrict__ att_m, const float* __restrict__ att_v,
    float* __restrict__ sc0, float* __restrict__ sh0,
    float* __restrict__ ftS, float* __restrict__ ftH,
    float* __restrict__ attS, float* __restrict__ attH)
{
    int idx = blockIdx.x * blockDim.x + threadIdx.x;
    if (idx < 512) {
        float s = bn0_g[idx] * rsqrtf(bn0_v[idx] + EPS_BN);
        sc0[idx] = s;
        sh0[idx] = bn0_b[idx] - bn0_m[idx] * s;
    } else if (idx < 512 + 24 * 512) {
        int q = idx - 512;
        int tb = q >> 9;
        int c = q & 511;
        int src = tb * 512 + glu_perm2(c);
        float s = ft_g[src] * rsqrtf(ft_v[src] + EPS_BN);
        ftS[q] = s;
        ftH[q] = ft_b[src] - ft_m[src] * s;
    } else if (idx < 512 + 24 * 512 + 5 * 512) {
        int q = idx - 512 - 24 * 512;
        float s = att_g[q] * rsqrtf(att_v[q] + EPS_BN);
        attS[q] = s;
        attH[q] = att_b[q] - att_m[q] * s;
    }
}

// Weight prep (batched over grid.y): src [K][512] fp32 -> dst [512][K] f16, optional GLU col-perm
__global__ void wprep_kernel(const float* __restrict__ src,
                             f16* __restrict__ dst, int K, int doperm)
{
    const int mat = blockIdx.y;
    src += (size_t)mat * K * 512;
    dst += (size_t)mat * 512 * K;
    int i = blockIdx.x * blockDim.x + threadIdx.x;
    if (i >= 512 * K) return;
    int n = i / K, k = i - n * K;
    int sn = doperm ? glu_perm2(n) : n;
    dst[i] = (f16)src[(size_t)k * 512 + sn];
}

// feats = bn0(features) -> f16; prior = 1 (fp32)
__global__ void bn0_split_kernel(const float* __restrict__ x,
                                 const float* __restrict__ sc,
                                 const float* __restrict__ sh,
                                 f16* __restrict__ fh,
                                 float* __restrict__ prior)
{
    int i = blockIdx.x * blockDim.x + threadIdx.x;   // over B*512/4
    int base = i * 4;
    int c = base & 511;
    float4 xv = *(const float4*)(x + base);
    f16x4 hv;
    hv.x = (f16)(xv.x * sc[c]     + sh[c]);
    hv.y = (f16)(xv.y * sc[c + 1] + sh[c + 1]);
    hv.z = (f16)(xv.z * sc[c + 2] + sh[c + 2]);
    hv.w = (f16)(xv.w * sc[c + 3] + sh[c + 3]);
    *(f16x4*)(fh + base) = hv;
    *(float4*)(prior + base) = make_float4(1.f, 1.f, 1.f, 1.f);
}

__global__ void zero_kernel(float4* __restrict__ p, int n4)
{
    int i = blockIdx.x * blockDim.x + threadIdx.x;
    if (i < n4) p[i] = make_float4(0.f, 0.f, 0.f, 0.f);
}

// ---------------- fp16 MFMA GEMM + fused epilogue ----------------
// Tile 128x128, BK=32, 4 waves (2x2), double-buffered LDS via global_load_lds.
// A: f16 [B][ldA]. B: f16 [512][K] pre-transposed (GLU-permuted for MODE<=2).
// Grid: 1024 blocks 1D, XCD-aware swizzle (4 col-blocks of a row-panel share an XCD).
// MODE 0: out = glu(bn(A@W))            -> f16 [B][256]
// MODE 1: out = res*sqrt(.5)+glu(bn(.)) -> f16 [B][256]
// MODE 2: MODE1 + oacc += relu(out) for oc<128
// MODE 3: outf = bn(A@W)                -> fp32 [B][512]
template<int MODE>
__global__ __launch_bounds__(256, 3) void gemm_mfma(
    const f16* __restrict__ A, int ldA, int K,
    const f16* __restrict__ B,
    const float* __restrict__ scale, const float* __restrict__ shift,
    const f16* __restrict__ res,
    f16* __restrict__ out,
    float* __restrict__ outf,
    float* __restrict__ oacc)
{
    __shared__ __align__(16) char smem[32768];   // 2 x 16KB buffers
    const int tid  = threadIdx.x;
    const int lane = tid & 63;
    const int w    = tid >> 6;        // wave 0..3
    const int wm   = w >> 1, wn = w & 1;
    // XCD-bijective swizzle: row-panel by -> XCD by%8; its 4 col-blocks adjacent in dispatch
    const int d    = blockIdx.x;
    const int by   = (d & 7) + 8 * (d >> 5);
    const int bx   = (d >> 3) & 3;
    const int brow = by * 128;
    const int bcol = bx * 128;
    const int lrow = lane & 15;
    const int lk8  = (lane >> 4) * 8;

    // staging: 8 A chunks (16 rows x 32k = 1KB each) + 8 B chunks; wave w owns chunks {2w,2w+1}
    const int c0 = 2 * w, c1 = 2 * w + 1;
    const char* gA0 = (const char*)(A + (size_t)(brow + c0 * 16 + lrow) * ldA + lk8);
    const char* gA1 = (const char*)(A + (size_t)(brow + c1 * 16 + lrow) * ldA + lk8);
    const char* gB0 = (const char*)(B + (size_t)(bcol + c0 * 16 + lrow) * K + lk8);
    const char* gB1 = (const char*)(B + (size_t)(bcol + c1 * 16 + lrow) * K + lk8);
    const int lA0 = c0 * 1024, lA1 = c1 * 1024;
    const int lB0 = 8192 + c0 * 1024, lB1 = 8192 + c1 * 1024;

    f32x4 acc[4][4];
    #pragma unroll
    for (int m = 0; m < 4; ++m)
        #pragma unroll
        for (int n = 0; n < 4; ++n)
            acc[m][n] = f32x4{0.f, 0.f, 0.f, 0.f};

    const int NT = K >> 5;
    gload16(gA0, smem + lA0);
    gload16(gA1, smem + lA1);
    gload16(gB0, smem + lB0);
    gload16(gB1, smem + lB1);

    for (int t = 0; t < NT; ++t) {
        __syncthreads();     // drains vmcnt: buf[t&1] staged; prior reads done
        if (t + 1 < NT) {
            const int bo = ((t + 1) & 1) * 16384;
            const int ko = (t + 1) * 64;            // 32 f16 = 64 bytes per tile
            gload16(gA0 + ko, smem + bo + lA0);
            gload16(gA1 + ko, smem + bo + lA1);
            gload16(gB0 + ko, smem + bo + lB0);
            gload16(gB1 + ko, smem + bo + lB1);
        }
        const char* L = smem + (t & 1) * 16384;
        f16x8 a[4];
        #pragma unroll
        for (int m = 0; m < 4; ++m)
            a[m] = *(const f16x8*)(L + (wm * 4 + m) * 1024 + lane * 16);
        #pragma unroll
        for (int n = 0; n < 4; ++n) {
            f16x8 b = *(const f16x8*)(L + 8192 + (wn * 4 + n) * 1024 + lane * 16);
            #pragma unroll
            for (int m = 0; m < 4; ++m)
                acc[m][n] = __builtin_amdgcn_mfma_f32_16x16x32_f16(a[m], b, acc[m][n], 0, 0, 0);
        }
    }

    // epilogue: D row' = (lane>>4)*4+r within 16-row frag, col' = lane&15
    if constexpr (MODE <= 2) {
        #pragma unroll
        for (int p = 0; p < 2; ++p) {
            const int cb = bcol + wn * 64 + p * 32;     // 32-col GLU group base
            const float sA = scale[cb + lrow],      hA = shift[cb + lrow];
            const float sB = scale[cb + 16 + lrow], hB = shift[cb + 16 + lrow];
            const int oc = (cb >> 1) + lrow;
            #pragma unroll
            for (int m = 0; m < 4; ++m) {
                const int row0 = brow + wm * 64 + m * 16 + (lane >> 4) * 4;
                #pragma unroll
                for (int r = 0; r < 4; ++r) {
                    const int row = row0 + r;
                    float y0 = acc[m][2 * p][r]     * sA + hA;
                    float y1 = acc[m][2 * p + 1][r] * sB + hB;
                    float val = y0 / (1.f + expf(-y1));
                    const size_t oi = (size_t)row * 256 + oc;
                    if constexpr (MODE >= 1)
                        val += SQRT_HALF * (float)res[oi];
                    out[oi] = (f16)val;
                    if constexpr (MODE == 2) {
                        if (oc < 128) oacc[(size_t)row * 128 + oc] += fmaxf(val, 0.f);
                    }
                }
            }
        }
    } else {
        #pragma unroll
        for (int n = 0; n < 4; ++n) {
            const int c = bcol + wn * 64 + n * 16 + lrow;
            const float sA = scale[c], hA = shift[c];
            #pragma unroll
            for (int m = 0; m < 4; ++m) {
                const int row0 = brow + wm * 64 + m * 16 + (lane >> 4) * 4;
                #pragma unroll
                for (int r = 0; r < 4; ++r)
                    outf[(size_t)(row0 + r) * 512 + c] = acc[m][n][r] * sA + hA;
            }
        }
    }
}

// ---------------- fused sparsemax ----------------
// attm (in d_out mask slot): holds att on entry, mask on exit.
__global__ __launch_bounds__(256) void sparsemax_kernel(
    const f16* __restrict__ fh,
    float* __restrict__ attm,
    float* __restrict__ prior,
    f16* __restrict__ mf)
{
    const int lane = threadIdx.x & 63;
    const int wid = threadIdx.x >> 6;
    const int row = blockIdx.x * 4 + wid;
    const size_t base = (size_t)row * 512 + lane;

    float z[8], pr[8];
    #pragma unroll
    for (int j = 0; j < 8; ++j) {
        pr[j] = prior[base + j * 64];
        z[j] = attm[base + j * 64] * pr[j];
    }
    float mx = z[0];
    #pragma unroll
    for (int j = 1; j < 8; ++j) mx = fmaxf(mx, z[j]);
    #pragma unroll
    for (int off = 32; off; off >>= 1) mx = fmaxf(mx, __shfl_xor(mx, off));

    float lo = mx - 1.0f, hi = mx;
    #pragma unroll 4
    for (int it = 0; it < 32; ++it) {
        float mid = 0.5f * (lo + hi);
        float s = 0.f;
        #pragma unroll
        for (int j = 0; j < 8; ++j) s += fmaxf(z[j] - mid, 0.f);
        #pragma unroll
        for (int off = 32; off; off >>= 1) s += __shfl_xor(s, off);
        if (s >= 1.0f) lo = mid; else hi = mid;
    }
    const float tau = lo;

    #pragma unroll
    for (int j = 0; j < 8; ++j) {
        const size_t ix = base + j * 64;
        float m = fmaxf(z[j] - tau, 0.f);
        attm[ix] = m;
        prior[ix] = pr[j] * (RELAX_C - m);
        mf[ix] = (f16)(m * (float)fh[ix]);
    }
}

// ---------------- final fp32 SIMT GEMM (K=128, N=128) ----------------
__global__ __launch_bounds__(256) void gemm_f32_final(
    const float* __restrict__ A,     // [B][128]
    const float* __restrict__ W,     // [128][128]
    const float* __restrict__ bias,
    float* __restrict__ out)         // [B][128]
{
    __shared__ float As[16][128];
    __shared__ float Bs[16][128];
    const int tid = threadIdx.x;
    const int tm = tid >> 4, tn = tid & 15;
    const int brow = blockIdx.x * 128;
    float acc[8][8] = {};
    for (int k0 = 0; k0 < 128; k0 += 16) {
        #pragma unroll
        for (int i = 0; i < 2; ++i) {
            int f = tid + i * 256;
            int row = f >> 2, kq = (f & 3) << 2;
            float4 av = *(const float4*)(A + (size_t)(brow + row) * 128 + k0 + kq);
            As[kq + 0][row] = av.x;
            As[kq + 1][row] = av.y;
            As[kq + 2][row] = av.z;
            As[kq + 3][row] = av.w;
            int kr = f >> 5, nq = (f & 31) << 2;
            *(float4*)(&Bs[kr][nq]) = *(const float4*)(W + (size_t)(k0 + kr) * 128 + nq);
        }
        __syncthreads();
        #pragma unroll
        for (int kk = 0; kk < 16; ++kk) {
            float a[8], b[8];
            *(float4*)(a)     = *(const float4*)(&As[kk][tm * 8]);
            *(float4*)(a + 4) = *(const float4*)(&As[kk][tm * 8 + 4]);
            *(float4*)(b)     = *(const float4*)(&Bs[kk][tn * 8]);
            *(float4*)(b + 4) = *(const float4*)(&Bs[kk][tn * 8 + 4]);
            #pragma unroll
            for (int i = 0; i < 8; ++i)
                #pragma unroll
                for (int j = 0; j < 8; ++j)
                    acc[i][j] += a[i] * b[j];
        }
        __syncthreads();
    }
    #pragma unroll
    for (int i = 0; i < 8; ++i) {
        int row = brow + tm * 8 + i;
        #pragma unroll
        for (int j = 0; j < 8; ++j)
            out[(size_t)row * 128 + tn * 8 + j] = acc[i][j] + bias[tn * 8 + j];
    }
}

// ---------------- launch ----------------
extern "C" void kernel_launch(void* const* d_in, const int* in_sizes, int n_in,
                              void* d_out, int out_size, void* d_ws, size_t ws_size,
                              hipStream_t stream)
{
    const float* features = (const float*)d_in[0];
    const float* bn0_g = (const float*)d_in[1];
    const float* bn0_b = (const float*)d_in[2];
    const float* bn0_m = (const float*)d_in[3];
    const float* bn0_v = (const float*)d_in[4];
    const float* Ws0   = (const float*)d_in[5];
    const float* Ws1   = (const float*)d_in[6];
    const float* Wu    = (const float*)d_in[7];
    const float* ft_g  = (const float*)d_in[8];
    const float* ft_b  = (const float*)d_in[9];
    const float* ft_m  = (const float*)d_in[10];
    const float* ft_v  = (const float*)d_in[11];
    const float* W_att = (const float*)d_in[12];
    const float* att_g = (const float*)d_in[13];
    const float* att_b = (const float*)d_in[14];
    const float* att_m = (const float*)d_in[15];
    const float* att_v = (const float*)d_in[16];
    const float* Wf    = (const float*)d_in[17];
    const float* bf    = (const float*)d_in[18];
    float* out = (float*)d_out;

    // ---- ws layout (bytes) ----
    char* wp = (char*)d_ws;
    auto alloc = [&](size_t bytes) { char* r = wp; wp += bytes; return r; };
    const size_t BR = B_ROWS;
    f16* feats  = (f16*)alloc(BR * 512 * 2);
    f16* ubuf   = (f16*)alloc(BR * 256 * 2);
    f16* vbuf   = (f16*)alloc(BR * 256 * 2);
    f16* attmf  = (f16*)alloc(BR * 512 * 2);
    float* prior = (float*)alloc(BR * 512 * 4);
    float* oacc  = (float*)alloc(BR * 128 * 4);
    f16* ws0  = (f16*)alloc(512 * 512 * 2);
    f16* ws1  = (f16*)alloc(512 * 256 * 2);
    f16* wu   = (f16*)alloc((size_t)12 * 512 * 256 * 2);
    f16* wat  = (f16*)alloc((size_t)5 * 512 * 128 * 2);
    float* ftS  = (float*)alloc(24 * 512 * 4);
    float* ftH  = (float*)alloc(24 * 512 * 4);
    float* attS = (float*)alloc(5 * 512 * 4);
    float* attH = (float*)alloc(5 * 512 * 4);
    float* sc0  = (float*)alloc(512 * 4);
    float* sh0  = (float*)alloc(512 * 4);

    // ---- prep ----
    prep_bn_kernel<<<60, 256, 0, stream>>>(
        bn0_g, bn0_b, bn0_m, bn0_v, ft_g, ft_b, ft_m, ft_v,
        att_g, att_b, att_m, att_v, sc0, sh0, ftS, ftH, attS, attH);
    wprep_kernel<<<dim3(512 * 512 / 256, 1), 256, 0, stream>>>(Ws0, ws0, 512, 1);
    wprep_kernel<<<dim3(512 * 256 / 256, 1), 256, 0, stream>>>(Ws1, ws1, 256, 1);
    wprep_kernel<<<dim3(512 * 256 / 256, 12), 256, 0, stream>>>(Wu, wu, 256, 1);
    wprep_kernel<<<dim3(512 * 128 / 256, 5), 256, 0, stream>>>(W_att, wat, 128, 0);
    bn0_split_kernel<<<(B_ROWS * 512 / 4) / 256, 256, 0, stream>>>(
        features, sc0, sh0, feats, prior);
    zero_kernel<<<(B_ROWS * 128 / 4) / 256, 256, 0, stream>>>((float4*)oacc, B_ROWS * 128 / 4);

    const int grid = 4 * (B_ROWS / 128);   // 1024 blocks, swizzled in-kernel

    auto ft = [&](const f16* in, int ldin, int Kin, int t, bool accum) {
        const f16* wu0 = wu + (size_t)(t * 2 + 0) * 131072;
        const f16* wu1 = wu + (size_t)(t * 2 + 1) * 131072;
        gemm_mfma<0><<<grid, 256, 0, stream>>>(in, ldin, Kin, ws0,
            ftS + (t * 4 + 0) * 512, ftH + (t * 4 + 0) * 512,
            nullptr, ubuf, nullptr, nullptr);
        gemm_mfma<1><<<grid, 256, 0, stream>>>(ubuf, 256, 256, ws1,
            ftS + (t * 4 + 1) * 512, ftH + (t * 4 + 1) * 512,
            ubuf, vbuf, nullptr, nullptr);
        gemm_mfma<1><<<grid, 256, 0, stream>>>(vbuf, 256, 256, wu0,
            ftS + (t * 4 + 2) * 512, ftH + (t * 4 + 2) * 512,
            vbuf, ubuf, nullptr, nullptr);
        if (accum)
            gemm_mfma<2><<<grid, 256, 0, stream>>>(ubuf, 256, 256, wu1,
                ftS + (t * 4 + 3) * 512, ftH + (t * 4 + 3) * 512,
                ubuf, vbuf, nullptr, oacc);
        else
            gemm_mfma<1><<<grid, 256, 0, stream>>>(ubuf, 256, 256, wu1,
                ftS + (t * 4 + 3) * 512, ftH + (t * 4 + 3) * 512,
                ubuf, vbuf, nullptr, nullptr);
    };

    ft(feats, 512, 512, 0, false);

    for (int s = 0; s < NSTEPS; ++s) {
        float* attm = out + 4194304 + (size_t)s * 16777216;   // att, then mask (in-place)
        gemm_mfma<3><<<grid, 256, 0, stream>>>(vbuf + 128, 256, 128,
            wat + (size_t)s * 65536,
            attS + s * 512, attH + s * 512,
            nullptr, nullptr, attm, nullptr);
        sparsemax_kernel<<<B_ROWS / 4, 256, 0, stream>>>(
            feats, attm, prior, attmf);
        ft(attmf, 512, 512, s + 1, true);
    }

    gemm_f32_final<<<B_ROWS / 128, 256, 0, stream>>>(oacc, Wf, bf, out);
}